// Round 1
// baseline (1748.745 us; speedup 1.0000x reference)
//
#include <hip/hip_runtime.h>
#include <hip/hip_bf16.h>

#define NN 98
#define CC 192
#define NH 6
#define HDIM 32
#define NWIN 64
#define MPAD 100
#define NSTR 200   // xs / O_lds row stride (bf16 elems): 400B, 16B-aligned rows
#define SWS 1920   // per-wave staging elems (3840B)

typedef float f32x4 __attribute__((ext_vector_type(4)));
typedef __bf16 bf16x8 __attribute__((ext_vector_type(8)));
typedef __bf16 bf16x4 __attribute__((ext_vector_type(4)));

__device__ __forceinline__ f32x4 mfma_bf16(bf16x8 a, bf16x8 b, f32x4 c) {
  return __builtin_amdgcn_mfma_f32_16x16x32_bf16(a, b, c, 0, 0, 0);
}

__device__ __forceinline__ bf16x8 zero8() {
  bf16x8 z;
#pragma unroll
  for (int i = 0; i < 8; ++i) z[i] = (__bf16)0.0f;
  return z;
}

// 8 contiguous fp32 from global -> bf16x8 fragment
__device__ __forceinline__ bf16x8 ldw8(const float* __restrict__ p) {
  f32x4 a = *(const f32x4*)p;
  f32x4 b = *(const f32x4*)(p + 4);
  bf16x8 r;
  r[0] = (__bf16)a[0]; r[1] = (__bf16)a[1]; r[2] = (__bf16)a[2]; r[3] = (__bf16)a[3];
  r[4] = (__bf16)b[0]; r[5] = (__bf16)b[1]; r[6] = (__bf16)b[2]; r[7] = (__bf16)b[3];
  return r;
}

// A-fragment from a [98][NSTR] LDS tile; rows >= 98 -> zero
__device__ __forceinline__ bf16x8 ldlds8(const __bf16* p, int row, int k0) {
  int rc = row < NN ? row : (NN - 1);
  bf16x8 v = *(const bf16x8*)(p + rc * NSTR + k0);
  if (row >= NN) v = zero8();
  return v;
}

// Pre-pad bias (gathered from rpb table) and mask to inner stride 100 with -1e30.
__global__ void prep_kernel(const float* __restrict__ mask,
                            const float* __restrict__ rpb,
                            const int* __restrict__ rel_idx,
                            float* __restrict__ biasp,
                            float* __restrict__ maskp) {
  int i = blockIdx.x * 256 + threadIdx.x;
  if (i < NH * NN * MPAD) {
    int m = i % MPAD;
    int rem = i / MPAD;
    int n = rem % NN;
    int h = rem / NN;
    biasp[i] = (m < NN) ? rpb[rel_idx[n * NN + m] * NH + h] : -1e30f;
  }
  if (i < NWIN * NN * MPAD) {
    int m = i % MPAD;
    int rem = i / MPAD;
    int n = rem % NN;
    int wi = rem / NN;
    maskp[i] = (m < NN) ? mask[(wi * NN + n) * NN + m] : -1e30f;
  }
}

__global__ __launch_bounds__(384, 3) void attn_kernel(
    const float* __restrict__ x,
    const float* __restrict__ qkv_w,
    const float* __restrict__ qkv_b,
    const float* __restrict__ proj_w,
    const float* __restrict__ proj_b,
    const float* __restrict__ biasp,
    const float* __restrict__ maskp,
    float* __restrict__ out) {
  __shared__ alignas(16) __bf16 xs[NN * NSTR];      // 39200 B; reused as O_lds after barrier
  __shared__ alignas(16) __bf16 stage[NH * SWS];    // 23040 B; per-wave private staging

  const int b = blockIdx.x;
  const int tid = threadIdx.x;
  const int w = tid >> 6;     // wave index == head index
  const int lane = tid & 63;
  const int l15 = lane & 15;
  const int quad = lane >> 4;
  __bf16* st = stage + w * SWS;

  // ---- stage x_b into LDS as bf16 ----
  const float* xb = x + (size_t)b * (NN * CC);
  for (int i = tid; i < NN * CC / 4; i += 384) {
    int e = i * 4;
    int n = e / CC;
    int c = e - n * CC;
    f32x4 v = *(const f32x4*)(xb + e);
    bf16x4 p;
    p[0] = (__bf16)v[0]; p[1] = (__bf16)v[1]; p[2] = (__bf16)v[2]; p[3] = (__bf16)v[3];
    *(bf16x4*)&xs[n * NSTR + c] = p;
  }
  __syncthreads();

  // ---- Phase A: K,V projection for head w (4 col-tiles x 7 row-tiles) ----
  f32x4 accA[4][7];
#pragma unroll
  for (int ct = 0; ct < 2; ++ct) {
    float bk = qkv_b[CC + w * HDIM + ct * 16 + l15];
    float bv = qkv_b[2 * CC + w * HDIM + ct * 16 + l15];
#pragma unroll
    for (int rt = 0; rt < 7; ++rt) {
      f32x4 tk = {bk, bk, bk, bk};
      f32x4 tv = {bv, bv, bv, bv};
      accA[ct][rt] = tk;
      accA[2 + ct][rt] = tv;
    }
  }
#pragma unroll
  for (int ks = 0; ks < 6; ++ks) {
    const int k0 = ks * 32 + quad * 8;
    bf16x8 b0 = ldw8(qkv_w + (size_t)(CC + w * HDIM + l15) * CC + k0);
    bf16x8 b1 = ldw8(qkv_w + (size_t)(CC + w * HDIM + 16 + l15) * CC + k0);
    bf16x8 b2 = ldw8(qkv_w + (size_t)(2 * CC + w * HDIM + l15) * CC + k0);
    bf16x8 b3 = ldw8(qkv_w + (size_t)(2 * CC + w * HDIM + 16 + l15) * CC + k0);
#pragma unroll
    for (int rt = 0; rt < 7; ++rt) {
      bf16x8 a = ldlds8(xs, rt * 16 + l15, k0);
      accA[0][rt] = mfma_bf16(a, b0, accA[0][rt]);
      accA[1][rt] = mfma_bf16(a, b1, accA[1][rt]);
      accA[2][rt] = mfma_bf16(a, b2, accA[2][rt]);
      accA[3][rt] = mfma_bf16(a, b3, accA[3][rt]);
    }
  }

  // ---- stage K tile-by-tile (wave-private [16][40]) -> A-frags ka[mt] ----
  bf16x8 ka[7];
#pragma unroll
  for (int rt = 0; rt < 7; ++rt) {
#pragma unroll
    for (int ct = 0; ct < 2; ++ct) {
      f32x4 v = accA[ct][rt];
      int hd = ct * 16 + l15;
#pragma unroll
      for (int r = 0; r < 4; ++r) st[(quad * 4 + r) * 40 + hd] = (__bf16)v[r];
    }
    bf16x8 f = *(const bf16x8*)&st[l15 * 40 + quad * 8];
    if (rt * 16 + l15 >= NN) f = zero8();
    ka[rt] = f;
  }

  // ---- stage V in row-tile pairs (wave-private [32][40]) -> A-frags va[dt][ks] ----
  bf16x8 va[2][4];
#pragma unroll
  for (int ks = 0; ks < 4; ++ks) {
#pragma unroll
    for (int h2 = 0; h2 < 2; ++h2) {
      int rt = 2 * ks + h2;
      if (rt < 7) {
#pragma unroll
        for (int ct = 0; ct < 2; ++ct) {
          f32x4 v = accA[2 + ct][rt];
          int d = ct * 16 + l15;
          int mloc = h2 * 16 + quad * 4;
          bf16x4 p;
#pragma unroll
          for (int r = 0; r < 4; ++r) p[r] = (__bf16)v[r];
          *(bf16x4*)&st[d * 40 + mloc] = p;
        }
      }
    }
#pragma unroll
    for (int dt = 0; dt < 2; ++dt) {
      bf16x8 f = *(const bf16x8*)&st[(dt * 16 + l15) * 40 + quad * 8];
      if (ks == 3 && quad >= 2) f = zero8();  // m >= 112 zeroed
      va[dt][ks] = f;
    }
  }

  // ---- Phase B: Q projection (2 col-tiles x 7 row-tiles) ----
  f32x4 accB[2][7];
#pragma unroll
  for (int ct = 0; ct < 2; ++ct) {
    float bq = qkv_b[w * HDIM + ct * 16 + l15];
#pragma unroll
    for (int rt = 0; rt < 7; ++rt) {
      f32x4 t = {bq, bq, bq, bq};
      accB[ct][rt] = t;
    }
  }
#pragma unroll
  for (int ks = 0; ks < 6; ++ks) {
    const int k0 = ks * 32 + quad * 8;
    bf16x8 b0 = ldw8(qkv_w + (size_t)(w * HDIM + l15) * CC + k0);
    bf16x8 b1 = ldw8(qkv_w + (size_t)(w * HDIM + 16 + l15) * CC + k0);
#pragma unroll
    for (int rt = 0; rt < 7; ++rt) {
      bf16x8 a = ldlds8(xs, rt * 16 + l15, k0);
      accB[0][rt] = mfma_bf16(a, b0, accB[0][rt]);
      accB[1][rt] = mfma_bf16(a, b1, accB[1][rt]);
    }
  }

  // ---- stage Q (scaled) tile-by-tile -> B-frags qb[nb] ----
  const float scale = 0.17677669529663687f;  // 32^-0.5
  bf16x8 qb[7];
#pragma unroll
  for (int rt = 0; rt < 7; ++rt) {
#pragma unroll
    for (int ct = 0; ct < 2; ++ct) {
      f32x4 v = accB[ct][rt];
      int hd = ct * 16 + l15;
#pragma unroll
      for (int r = 0; r < 4; ++r) st[(quad * 4 + r) * 40 + hd] = (__bf16)(v[r] * scale);
    }
    bf16x8 f = *(const bf16x8*)&st[l15 * 40 + quad * 8];
    if (rt * 16 + l15 >= NN) f = zero8();
    qb[rt] = f;
  }

  __syncthreads();  // all waves done reading xs; it becomes O_lds
  __bf16* O_lds = xs;

  // ---- attention: S^T = K Q^T per 16-column block; lane-local softmax; O^T = V^T P^T ----
  const int wmask = b & (NWIN - 1);
#pragma unroll 1
  for (int nb = 0; nb < 7; ++nb) {
    f32x4 sacc[7];
    const f32x4 z4 = {0.f, 0.f, 0.f, 0.f};
#pragma unroll
    for (int mt = 0; mt < 7; ++mt) sacc[mt] = mfma_bf16(ka[mt], qb[nb], z4);

    int n = nb * 16 + l15;
    bool nvalid = (n < NN);
    int nc = nvalid ? n : 0;
    const float* bp = biasp + (size_t)(w * NN + nc) * MPAD;
    const float* mp = maskp + (size_t)(wmask * NN + nc) * MPAD;

    float sv[28];
    float mx = -3.0e38f;
#pragma unroll
    for (int mt = 0; mt < 7; ++mt) {
      int m0 = mt * 16 + quad * 4;
      f32x4 add = z4;
      bool ld = nvalid && (m0 < MPAD);
      if (ld) {
        f32x4 bm = *(const f32x4*)(bp + m0);
        f32x4 mm = *(const f32x4*)(mp + m0);
        add = bm + mm;  // padded entries are -1e30
      }
#pragma unroll
      for (int r = 0; r < 4; ++r) {
        float v = ld ? (sacc[mt][r] + add[r]) : -1e30f;
        sv[mt * 4 + r] = v;
        mx = fmaxf(mx, v);
      }
    }
    mx = fmaxf(mx, __shfl_xor(mx, 16, 64));
    mx = fmaxf(mx, __shfl_xor(mx, 32, 64));
    float sum = 0.f;
#pragma unroll
    for (int i = 0; i < 28; ++i) {
      float p = __expf(sv[i] - mx);
      sv[i] = p;
      sum += p;
    }
    sum += __shfl_xor(sum, 16, 64);
    sum += __shfl_xor(sum, 32, 64);
    float rinv = 1.0f / sum;

    // write P^T to wave-private [16][120] LDS, reload as B-frags
#pragma unroll
    for (int mt = 0; mt < 7; ++mt) {
      bf16x4 p;
#pragma unroll
      for (int r = 0; r < 4; ++r) p[r] = (__bf16)sv[mt * 4 + r];
      *(bf16x4*)&st[l15 * 120 + mt * 16 + quad * 4] = p;
    }
    bf16x8 pf[4];
#pragma unroll
    for (int ks = 0; ks < 4; ++ks) {
      bf16x8 f = *(const bf16x8*)&st[l15 * 120 + ks * 32 + quad * 8];
      if (ks == 3 && quad >= 2) f = zero8();
      pf[ks] = f;
    }

#pragma unroll
    for (int dt = 0; dt < 2; ++dt) {
      f32x4 o = z4;
#pragma unroll
      for (int ks = 0; ks < 4; ++ks) o = mfma_bf16(va[dt][ks], pf[ks], o);
      if (nvalid) {
        bf16x4 p;
#pragma unroll
        for (int r = 0; r < 4; ++r) p[r] = (__bf16)(o[r] * rinv);
        *(bf16x4*)&O_lds[n * NSTR + w * HDIM + dt * 16 + quad * 4] = p;
      }
    }
  }
  __syncthreads();  // O_lds complete

  // ---- output projection: out = O @ proj_w^T + proj_b ----
  f32x4 accP[2][7];
#pragma unroll
  for (int ct = 0; ct < 2; ++ct) {
    float pb = proj_b[w * HDIM + ct * 16 + l15];
#pragma unroll
    for (int rt = 0; rt < 7; ++rt) {
      f32x4 t = {pb, pb, pb, pb};
      accP[ct][rt] = t;
    }
  }
#pragma unroll
  for (int ks = 0; ks < 6; ++ks) {
    const int k0 = ks * 32 + quad * 8;
    bf16x8 b0 = ldw8(proj_w + (size_t)(w * HDIM + l15) * CC + k0);
    bf16x8 b1 = ldw8(proj_w + (size_t)(w * HDIM + 16 + l15) * CC + k0);
#pragma unroll
    for (int rt = 0; rt < 7; ++rt) {
      bf16x8 a = ldlds8(O_lds, rt * 16 + l15, k0);
      accP[0][rt] = mfma_bf16(a, b0, accP[0][rt]);
      accP[1][rt] = mfma_bf16(a, b1, accP[1][rt]);
    }
  }

  float* ob = out + (size_t)b * (NN * CC);
#pragma unroll
  for (int ct = 0; ct < 2; ++ct) {
    int cout = w * HDIM + ct * 16 + l15;
#pragma unroll
    for (int rt = 0; rt < 7; ++rt) {
      f32x4 v = accP[ct][rt];
#pragma unroll
      for (int r = 0; r < 4; ++r) {
        int n = rt * 16 + quad * 4 + r;
        if (n < NN) ob[n * CC + cout] = v[r];
      }
    }
  }
}

extern "C" void kernel_launch(void* const* d_in, const int* in_sizes, int n_in,
                              void* d_out, int out_size, void* d_ws, size_t ws_size,
                              hipStream_t stream) {
  const float* x = (const float*)d_in[0];
  const float* mask = (const float*)d_in[1];
  const float* qkv_w = (const float*)d_in[2];
  const float* qkv_b = (const float*)d_in[3];
  const float* proj_w = (const float*)d_in[4];
  const float* proj_b = (const float*)d_in[5];
  const float* rpb = (const float*)d_in[6];
  const int* rel_idx = (const int*)d_in[7];

  float* biasp = (float*)d_ws;                       // 6*98*100 floats
  float* maskp = biasp + NH * NN * MPAD;             // 64*98*100 floats

  int prep_threads = NWIN * NN * MPAD;               // 627200
  prep_kernel<<<(prep_threads + 255) / 256, 256, 0, stream>>>(mask, rpb, rel_idx, biasp, maskp);
  attn_kernel<<<4096, 384, 0, stream>>>(x, qkv_w, qkv_b, proj_w, proj_b, biasp, maskp,
                                        (float*)d_out);
}